// Round 6
// baseline (238.180 us; speedup 1.0000x reference)
//
#include <hip/hip_runtime.h>

#define N_NODES 100000
#define IN_C    128
#define HID_C   64
#define OUT_C   40
#define N_EDGES 1600000
#define G2_STRIDE 64   // padded row (halfs) -> 128B, one cache line per gather

// bucketed CSR build
#define BSH        8
#define NBUCK      ((N_NODES + 255) >> BSH)              // 391 buckets of 256 nodes
#define PART_CHUNK 4096
#define NPB        ((N_EDGES + PART_CHUNK - 1) / PART_CHUNK)  // 391
#define EPT        (PART_CHUNK / 256)

// node-count scan
#define SCAN_ITEMS 1024
#define NB ((N_NODES + SCAN_ITEMS - 1) / SCAN_ITEMS)     // 98

typedef _Float16 half_t;
typedef _Float16 half8   __attribute__((ext_vector_type(8)));
typedef _Float16 half2_t __attribute__((ext_vector_type(2)));
typedef float    f32x4   __attribute__((ext_vector_type(4)));

static __device__ __forceinline__ void acc_u2(float4& a, uint2 v, bool ok) {
    half2_t h0 = __builtin_bit_cast(half2_t, v.x);
    half2_t h1 = __builtin_bit_cast(half2_t, v.y);
    if (ok) {
        a.x += (float)h0.x; a.y += (float)h0.y;
        a.z += (float)h1.x; a.w += (float)h1.y;
    }
}

// ---------------------------------------------------------------------------
// init: zero bucket counts + transpose W1 -> W1T [64][128] fp16
// ---------------------------------------------------------------------------
__global__ void k_init(const float* __restrict__ W1, half_t* __restrict__ W1T,
                       int* __restrict__ bcnt) {
    int t = threadIdx.x;  // 512
    if (t < NBUCK) bcnt[t] = 0;
    for (int i = t; i < IN_C * HID_C; i += 512) {
        int k = i >> 6, n = i & 63;
        W1T[n * IN_C + k] = (half_t)W1[i];
    }
}

__global__ void k_hist(const int* __restrict__ dst, int* __restrict__ bcnt) {
    __shared__ int lh[NBUCK];
    int tid = threadIdx.x;
    for (int i = tid; i < NBUCK; i += 256) lh[i] = 0;
    __syncthreads();
    int base = blockIdx.x * PART_CHUNK;
#pragma unroll
    for (int j = 0; j < EPT; ++j) {
        int e = base + j * 256 + tid;
        if (e < N_EDGES) atomicAdd(&lh[dst[e] >> BSH], 1);
    }
    __syncthreads();
    for (int i = tid; i < NBUCK; i += 256)
        if (lh[i]) atomicAdd(&bcnt[i], lh[i]);
}

__global__ void k_bscan(const int* __restrict__ bcnt, int* __restrict__ bstart,
                        int* __restrict__ gcur) {
    __shared__ int s[512];
    int tid = threadIdx.x;
    int v = (tid < NBUCK) ? bcnt[tid] : 0;
    s[tid] = v;
    __syncthreads();
    for (int off = 1; off < 512; off <<= 1) {
        int t = (tid >= off) ? s[tid - off] : 0;
        __syncthreads();
        s[tid] += t;
        __syncthreads();
    }
    if (tid < NBUCK) {
        int excl = s[tid] - v;
        bstart[tid] = excl;
        gcur[tid]   = excl;
    }
    if (tid == 0) bstart[NBUCK] = N_EDGES;
}

__global__ void k_part(const int* __restrict__ src, const int* __restrict__ dst,
                       int* __restrict__ gcur, unsigned long long* __restrict__ pairs) {
    __shared__ int lh[NBUCK];
    int tid = threadIdx.x;
    for (int i = tid; i < NBUCK; i += 256) lh[i] = 0;
    __syncthreads();
    int base = blockIdx.x * PART_CHUNK;
    int sv[EPT], dv[EPT], rv[EPT];
#pragma unroll
    for (int j = 0; j < EPT; ++j) {
        int e = base + j * 256 + tid;
        if (e < N_EDGES) {
            sv[j] = src[e];
            dv[j] = dst[e];
            rv[j] = atomicAdd(&lh[dv[j] >> BSH], 1);
        } else {
            dv[j] = -1;
        }
    }
    __syncthreads();
    for (int i = tid; i < NBUCK; i += 256) {
        int c = lh[i];
        if (c) lh[i] = atomicAdd(&gcur[i], c);
    }
    __syncthreads();
#pragma unroll
    for (int j = 0; j < EPT; ++j) {
        if (dv[j] >= 0) {
            int pos = lh[dv[j] >> BSH] + rv[j];
            pairs[pos] = ((unsigned long long)(unsigned)dv[j] << 32) | (unsigned)sv[j];
        }
    }
}

__global__ void k_bcount(const unsigned long long* __restrict__ pairs,
                         const int* __restrict__ bstart, int* __restrict__ cnt) {
    __shared__ int lc[256];
    int b = blockIdx.x, tid = threadIdx.x;
    lc[tid] = 0;
    __syncthreads();
    int s0 = bstart[b], s1 = bstart[b + 1];
    int nbase = b << BSH;
    for (int e = s0 + tid; e < s1; e += 256)
        atomicAdd(&lc[(int)(pairs[e] >> 32) - nbase], 1);
    __syncthreads();
    int node = nbase + tid;
    if (node < N_NODES) cnt[node] = lc[tid];
}

__global__ void k_scan_blk(const int* __restrict__ cnt, int* __restrict__ cursor,
                           int* __restrict__ blks) {
    __shared__ int s[256];
    int tid = threadIdx.x;
    int base = blockIdx.x * SCAN_ITEMS + tid * 4;
    int a0 = (base + 0 < N_NODES) ? cnt[base + 0] : 0;
    int a1 = (base + 1 < N_NODES) ? cnt[base + 1] : 0;
    int a2 = (base + 2 < N_NODES) ? cnt[base + 2] : 0;
    int a3 = (base + 3 < N_NODES) ? cnt[base + 3] : 0;
    int tsum = a0 + a1 + a2 + a3;
    s[tid] = tsum;
    __syncthreads();
    for (int off = 1; off < 256; off <<= 1) {
        int t = (tid >= off) ? s[tid - off] : 0;
        __syncthreads();
        s[tid] += t;
        __syncthreads();
    }
    int texcl = s[tid] - tsum;
    if (base + 0 < N_NODES) cursor[base + 0] = texcl;
    if (base + 1 < N_NODES) cursor[base + 1] = texcl + a0;
    if (base + 2 < N_NODES) cursor[base + 2] = texcl + a0 + a1;
    if (base + 3 < N_NODES) cursor[base + 3] = texcl + a0 + a1 + a2;
    if (tid == 0) blks[blockIdx.x] = s[255];
}

__global__ void k_scan_top(int* __restrict__ blks) {
    __shared__ int s[128];
    int tid = threadIdx.x;
    int v = (tid < NB) ? blks[tid] : 0;
    s[tid] = v;
    __syncthreads();
    for (int off = 1; off < 128; off <<= 1) {
        int t = (tid >= off) ? s[tid - off] : 0;
        __syncthreads();
        s[tid] += t;
        __syncthreads();
    }
    if (tid < NB) blks[tid] = s[tid] - v;
}

__global__ void k_scan_add(const int* __restrict__ cnt, int* __restrict__ cursor,
                           const int* __restrict__ blks, float* __restrict__ dinv) {
    int tid = threadIdx.x;
    int base = blockIdx.x * SCAN_ITEMS + tid * 4;
    int off = blks[blockIdx.x];
#pragma unroll
    for (int j = 0; j < 4; ++j) {
        int i = base + j;
        if (i < N_NODES) {
            cursor[i] += off;
            dinv[i] = rsqrtf(1.0f + (float)cnt[i]);
        }
    }
}

__global__ void k_bfill(const unsigned long long* __restrict__ pairs,
                        const int* __restrict__ bstart, const int* __restrict__ cursor,
                        int* __restrict__ esrc) {
    __shared__ int lcur[256];
    int b = blockIdx.x, tid = threadIdx.x;
    int nbase = b << BSH;
    int node = nbase + tid;
    lcur[tid] = (node < N_NODES) ? cursor[node] : 0;
    __syncthreads();
    int s0 = bstart[b], s1 = bstart[b + 1];
    for (int e = s0 + tid; e < s1; e += 256) {
        unsigned long long p = pairs[e];
        int d = (int)(p >> 32);
        int s = (int)(p & 0xffffffffu);
        int pos = atomicAdd(&lcur[d - nbase], 1);
        esrc[pos] = s;
    }
}

// ---------------------------------------------------------------------------
// MFMA GEMM1: g1[n,c] = fp16( dinv[n] * (x[n,:] @ W1)[c] )
// ---------------------------------------------------------------------------
__global__ void k_gemm1_mfma(const float* __restrict__ x, const half_t* __restrict__ W1T,
                             const float* __restrict__ dinv, half_t* __restrict__ g1) {
    int lane = threadIdx.x & 63;
    int l16  = lane & 15;
    int lg   = lane >> 4;

    half8 bf[4][4];
#pragma unroll
    for (int ct = 0; ct < 4; ++ct)
#pragma unroll
        for (int kc = 0; kc < 4; ++kc)
            bf[ct][kc] = *(const half8*)(W1T + (ct * 16 + l16) * IN_C + kc * 32 + lg * 8);

#pragma unroll
    for (int s = 0; s < 2; ++s) {
        int r0 = (blockIdx.x * 2 + s) * 16;
        f32x4 acc0 = {0.f, 0.f, 0.f, 0.f};
        f32x4 acc1 = {0.f, 0.f, 0.f, 0.f};
        f32x4 acc2 = {0.f, 0.f, 0.f, 0.f};
        f32x4 acc3 = {0.f, 0.f, 0.f, 0.f};
#pragma unroll
        for (int kc = 0; kc < 4; ++kc) {
            const float* ap = x + (size_t)(r0 + l16) * IN_C + kc * 32 + lg * 8;
            float4 a0 = *(const float4*)ap;
            float4 a1 = *(const float4*)(ap + 4);
            half8 af;
            af[0] = (_Float16)a0.x; af[1] = (_Float16)a0.y;
            af[2] = (_Float16)a0.z; af[3] = (_Float16)a0.w;
            af[4] = (_Float16)a1.x; af[5] = (_Float16)a1.y;
            af[6] = (_Float16)a1.z; af[7] = (_Float16)a1.w;
            acc0 = __builtin_amdgcn_mfma_f32_16x16x32_f16(af, bf[0][kc], acc0, 0, 0, 0);
            acc1 = __builtin_amdgcn_mfma_f32_16x16x32_f16(af, bf[1][kc], acc1, 0, 0, 0);
            acc2 = __builtin_amdgcn_mfma_f32_16x16x32_f16(af, bf[2][kc], acc2, 0, 0, 0);
            acc3 = __builtin_amdgcn_mfma_f32_16x16x32_f16(af, bf[3][kc], acc3, 0, 0, 0);
        }
        float dv[4];
#pragma unroll
        for (int j = 0; j < 4; ++j) dv[j] = dinv[r0 + lg * 4 + j];
#pragma unroll
        for (int j = 0; j < 4; ++j) {
            size_t rb = (size_t)(r0 + lg * 4 + j) * HID_C;
            g1[rb +  0 + l16] = (half_t)(acc0[j] * dv[j]);
            g1[rb + 16 + l16] = (half_t)(acc1[j] * dv[j]);
            g1[rb + 32 + l16] = (half_t)(acc2[j] * dv[j]);
            g1[rb + 48 + l16] = (half_t)(acc3[j] * dv[j]);
        }
    }
}

// ---------------------------------------------------------------------------
// pull layer1 + fused 64->40 GEMM.
// Wave = 1 node; 4 slots x 16 lanes; each slot gathers one edge row as
// uint2 (8B/lane, 128B/slot) -> one load instr covers 4 edges (512B).
// Main body keeps 4 loads (16 edges, 2KB) in flight. Butterfly combine.
// ---------------------------------------------------------------------------
__global__ void k_pull1(const int* __restrict__ cursor, const int* __restrict__ cnt,
                        const int* __restrict__ esrc, const float* __restrict__ dinv,
                        const half_t* __restrict__ g1, const float* __restrict__ b1,
                        const float* __restrict__ W2, half_t* __restrict__ g2) {
    __shared__ float lds[4][HID_C];
    int w    = threadIdx.x >> 6;
    int lane = threadIdx.x & 63;
    int n    = blockIdx.x * 4 + w;
    int h    = lane >> 4;    // slot 0..3
    int c4   = lane & 15;    // channel quad (4 halfs)
    const uint2* g1v = (const uint2*)g1;   // row = 16 uint2

    float dn  = dinv[n];
    int start = cursor[n];
    int end   = start + cnt[n];

    float4 acc = {0.f, 0.f, 0.f, 0.f};
    if (h == 0) acc_u2(acc, g1v[(size_t)n * 16 + c4], true);  // self row

    int e = start;
    for (; e + 16 <= end; e += 16) {
        int i0 = esrc[e + h];
        int i1 = esrc[e + h + 4];
        int i2 = esrc[e + h + 8];
        int i3 = esrc[e + h + 12];
        uint2 v0 = g1v[(size_t)i0 * 16 + c4];
        uint2 v1 = g1v[(size_t)i1 * 16 + c4];
        uint2 v2 = g1v[(size_t)i2 * 16 + c4];
        uint2 v3 = g1v[(size_t)i3 * 16 + c4];
        acc_u2(acc, v0, true); acc_u2(acc, v1, true);
        acc_u2(acc, v2, true); acc_u2(acc, v3, true);
    }
    for (; e < end; e += 4) {
        int  ee = e + h;
        bool ok = ee < end;
        int  idx = esrc[ok ? ee : end - 1];
        uint2 v = g1v[(size_t)idx * 16 + c4];
        acc_u2(acc, v, ok);
    }

    // butterfly over slot bits: every lane gets full channel-quad sum
    acc.x += __shfl_xor(acc.x, 16); acc.y += __shfl_xor(acc.y, 16);
    acc.z += __shfl_xor(acc.z, 16); acc.w += __shfl_xor(acc.w, 16);
    acc.x += __shfl_xor(acc.x, 32); acc.y += __shfl_xor(acc.y, 32);
    acc.z += __shfl_xor(acc.z, 32); acc.w += __shfl_xor(acc.w, 32);

    if (h == 0) {
        float4 bb = ((const float4*)b1)[c4];
        float4 r;
        r.x = fmaxf(dn * acc.x + bb.x, 0.0f);
        r.y = fmaxf(dn * acc.y + bb.y, 0.0f);
        r.z = fmaxf(dn * acc.z + bb.z, 0.0f);
        r.w = fmaxf(dn * acc.w + bb.w, 0.0f);
        ((float4*)lds[w])[c4] = r;
    }
    // wave-private LDS; same-wave write->read ordering handled by compiler
    float s = 0.0f;
#pragma unroll
    for (int c = 0; c < HID_C; ++c)
        s += lds[w][c] * W2[c * OUT_C + (lane < OUT_C ? lane : 0)];
    // padded g2 row: lanes 0..39 value, 40..63 zero
    g2[(size_t)n * G2_STRIDE + lane] = (lane < OUT_C) ? (half_t)(dn * s) : (half_t)0.0f;
}

// ---------------------------------------------------------------------------
// pull layer2 -> out. Padded 128B rows: 4 slots x 16 lanes x uint2.
// Padding halfs are zero so accumulation is unconditional.
// ---------------------------------------------------------------------------
__global__ void k_pull2(const int* __restrict__ cursor, const int* __restrict__ cnt,
                        const int* __restrict__ esrc, const float* __restrict__ dinv,
                        const half_t* __restrict__ g2, const float* __restrict__ b2,
                        float* __restrict__ out) {
    int w    = threadIdx.x >> 6;
    int lane = threadIdx.x & 63;
    int n    = blockIdx.x * 4 + w;
    int h    = lane >> 4;
    int c4   = lane & 15;
    const uint2* g2v = (const uint2*)g2;   // row = 16 uint2 (padded)

    float dn  = dinv[n];
    int start = cursor[n];
    int end   = start + cnt[n];

    float4 acc = {0.f, 0.f, 0.f, 0.f};
    if (h == 0) acc_u2(acc, g2v[(size_t)n * 16 + c4], true);  // self row

    int e = start;
    for (; e + 16 <= end; e += 16) {
        int i0 = esrc[e + h];
        int i1 = esrc[e + h + 4];
        int i2 = esrc[e + h + 8];
        int i3 = esrc[e + h + 12];
        uint2 v0 = g2v[(size_t)i0 * 16 + c4];
        uint2 v1 = g2v[(size_t)i1 * 16 + c4];
        uint2 v2 = g2v[(size_t)i2 * 16 + c4];
        uint2 v3 = g2v[(size_t)i3 * 16 + c4];
        acc_u2(acc, v0, true); acc_u2(acc, v1, true);
        acc_u2(acc, v2, true); acc_u2(acc, v3, true);
    }
    for (; e < end; e += 4) {
        int  ee = e + h;
        bool ok = ee < end;
        int  idx = esrc[ok ? ee : end - 1];
        uint2 v = g2v[(size_t)idx * 16 + c4];
        acc_u2(acc, v, ok);
    }

    acc.x += __shfl_xor(acc.x, 16); acc.y += __shfl_xor(acc.y, 16);
    acc.z += __shfl_xor(acc.z, 16); acc.w += __shfl_xor(acc.w, 16);
    acc.x += __shfl_xor(acc.x, 32); acc.y += __shfl_xor(acc.y, 32);
    acc.z += __shfl_xor(acc.z, 32); acc.w += __shfl_xor(acc.w, 32);

    if (h == 0 && c4 < 10) {   // 10 quads = 40 channels
        float4 bb = ((const float4*)b2)[c4];
        float4 r;
        r.x = bb.x + dn * acc.x;
        r.y = bb.y + dn * acc.y;
        r.z = bb.z + dn * acc.z;
        r.w = bb.w + dn * acc.w;
        ((float4*)(out + (size_t)n * OUT_C))[c4] = r;
    }
}

// ---------------------------------------------------------------------------
// launch
// ---------------------------------------------------------------------------
extern "C" void kernel_launch(void* const* d_in, const int* in_sizes, int n_in,
                              void* d_out, int out_size, void* d_ws, size_t ws_size,
                              hipStream_t stream) {
    const float* x   = (const float*)d_in[0];
    const int*   ei  = (const int*)d_in[1];
    const int*   src = ei;
    const int*   dst = ei + N_EDGES;
    const float* W1  = (const float*)d_in[2];
    const float* b1  = (const float*)d_in[3];
    const float* W2  = (const float*)d_in[4];
    const float* b2  = (const float*)d_in[5];
    float*       out = (float*)d_out;

    // workspace layout (~33 MB)
    int*    cnt    = (int*)d_ws;                      // N
    int*    cursor = cnt + N_NODES;                   // N
    int*    blks   = cursor + N_NODES;                // 128
    int*    bcnt   = blks + 128;                      // NBUCK
    int*    bstart = bcnt + NBUCK;                    // NBUCK+1
    int*    gcur   = bstart + NBUCK + 1;              // NBUCK
    half_t* w1t    = (half_t*)(gcur + NBUCK);         // 128*64 halves (16KB)
    float*  dinv   = (float*)(w1t + IN_C * HID_C);    // N
    int*    esrc   = (int*)(dinv + N_NODES);          // E
    int*    after  = esrc + N_EDGES;
    unsigned long long* pairs =
        (unsigned long long*)(((uintptr_t)after + 15) & ~(uintptr_t)15);  // E * 8B
    half_t* g1 = (half_t*)pairs;                      // overlays pairs (12.8MB)
    half_t* g2 = (half_t*)(pairs + N_EDGES);          // N * G2_STRIDE halves (12.8MB)

    // CSR build (bucketed)
    k_init<<<1, 512, 0, stream>>>(W1, w1t, bcnt);
    k_hist<<<NPB, 256, 0, stream>>>(dst, bcnt);
    k_bscan<<<1, 512, 0, stream>>>(bcnt, bstart, gcur);
    k_part<<<NPB, 256, 0, stream>>>(src, dst, gcur, pairs);
    k_bcount<<<NBUCK, 256, 0, stream>>>(pairs, bstart, cnt);
    k_scan_blk<<<NB, 256, 0, stream>>>(cnt, cursor, blks);
    k_scan_top<<<1, 128, 0, stream>>>(blks);
    k_scan_add<<<NB, 256, 0, stream>>>(cnt, cursor, blks, dinv);
    k_bfill<<<NBUCK, 256, 0, stream>>>(pairs, bstart, cursor, esrc);

    // layer 1 transform: g1 = dinv * (x @ W1)  [fp16, MFMA]
    k_gemm1_mfma<<<N_NODES / 32, 64, 0, stream>>>(x, w1t, dinv, g1);

    // pull layer 1 + fused GEMM2
    k_pull1<<<N_NODES / 4, 256, 0, stream>>>(cursor, cnt, esrc, dinv, g1, b1, W2, g2);

    // pull layer 2
    k_pull2<<<N_NODES / 4, 256, 0, stream>>>(cursor, cnt, esrc, dinv, g2, b2, out);
}

// Round 7
// 217.307 us; speedup vs baseline: 1.0961x; 1.0961x over previous
//
#include <hip/hip_runtime.h>

#define N_NODES 100000
#define IN_C    128
#define HID_C   64
#define OUT_C   40
#define N_EDGES 1600000

// bucketed CSR build
#define BSH        8
#define NBUCK      ((N_NODES + 255) >> BSH)              // 391 buckets of 256 nodes
#define PART_CHUNK 4096
#define NPB        ((N_EDGES + PART_CHUNK - 1) / PART_CHUNK)  // 391
#define EPT        (PART_CHUNK / 256)

// node-count scan
#define SCAN_ITEMS 1024
#define NB ((N_NODES + SCAN_ITEMS - 1) / SCAN_ITEMS)     // 98

typedef _Float16 half_t;
typedef _Float16 half8   __attribute__((ext_vector_type(8)));
typedef _Float16 half2_t __attribute__((ext_vector_type(2)));
typedef float    f32x4   __attribute__((ext_vector_type(4)));

static __device__ __forceinline__ void acc_pair(float2& a, unsigned v) {
    half2_t h = __builtin_bit_cast(half2_t, v);
    a.x += (float)h.x;
    a.y += (float)h.y;
}

// dequant-accumulate 4 int8 channels with row scale
static __device__ __forceinline__ void acc_q(float4& a, unsigned v, float sc, bool ok) {
    char4 c = __builtin_bit_cast(char4, v);
    if (ok) {
        a.x += sc * (float)c.x;
        a.y += sc * (float)c.y;
        a.z += sc * (float)c.z;
        a.w += sc * (float)c.w;
    }
}

// ---------------------------------------------------------------------------
// init: zero bucket counts + transpose W1 -> W1T [64][128] fp16
// ---------------------------------------------------------------------------
__global__ void k_init(const float* __restrict__ W1, half_t* __restrict__ W1T,
                       int* __restrict__ bcnt) {
    int t = threadIdx.x;  // 512
    if (t < NBUCK) bcnt[t] = 0;
    for (int i = t; i < IN_C * HID_C; i += 512) {
        int k = i >> 6, n = i & 63;
        W1T[n * IN_C + k] = (half_t)W1[i];
    }
}

__global__ void k_hist(const int* __restrict__ dst, int* __restrict__ bcnt) {
    __shared__ int lh[NBUCK];
    int tid = threadIdx.x;
    for (int i = tid; i < NBUCK; i += 256) lh[i] = 0;
    __syncthreads();
    int base = blockIdx.x * PART_CHUNK;
#pragma unroll
    for (int j = 0; j < EPT; ++j) {
        int e = base + j * 256 + tid;
        if (e < N_EDGES) atomicAdd(&lh[dst[e] >> BSH], 1);
    }
    __syncthreads();
    for (int i = tid; i < NBUCK; i += 256)
        if (lh[i]) atomicAdd(&bcnt[i], lh[i]);
}

__global__ void k_bscan(const int* __restrict__ bcnt, int* __restrict__ bstart,
                        int* __restrict__ gcur) {
    __shared__ int s[512];
    int tid = threadIdx.x;
    int v = (tid < NBUCK) ? bcnt[tid] : 0;
    s[tid] = v;
    __syncthreads();
    for (int off = 1; off < 512; off <<= 1) {
        int t = (tid >= off) ? s[tid - off] : 0;
        __syncthreads();
        s[tid] += t;
        __syncthreads();
    }
    if (tid < NBUCK) {
        int excl = s[tid] - v;
        bstart[tid] = excl;
        gcur[tid]   = excl;
    }
    if (tid == 0) bstart[NBUCK] = N_EDGES;
}

__global__ void k_part(const int* __restrict__ src, const int* __restrict__ dst,
                       int* __restrict__ gcur, unsigned long long* __restrict__ pairs) {
    __shared__ int lh[NBUCK];
    int tid = threadIdx.x;
    for (int i = tid; i < NBUCK; i += 256) lh[i] = 0;
    __syncthreads();
    int base = blockIdx.x * PART_CHUNK;
    int sv[EPT], dv[EPT], rv[EPT];
#pragma unroll
    for (int j = 0; j < EPT; ++j) {
        int e = base + j * 256 + tid;
        if (e < N_EDGES) {
            sv[j] = src[e];
            dv[j] = dst[e];
            rv[j] = atomicAdd(&lh[dv[j] >> BSH], 1);
        } else {
            dv[j] = -1;
        }
    }
    __syncthreads();
    for (int i = tid; i < NBUCK; i += 256) {
        int c = lh[i];
        if (c) lh[i] = atomicAdd(&gcur[i], c);
    }
    __syncthreads();
#pragma unroll
    for (int j = 0; j < EPT; ++j) {
        if (dv[j] >= 0) {
            int pos = lh[dv[j] >> BSH] + rv[j];
            pairs[pos] = ((unsigned long long)(unsigned)dv[j] << 32) | (unsigned)sv[j];
        }
    }
}

__global__ void k_bcount(const unsigned long long* __restrict__ pairs,
                         const int* __restrict__ bstart, int* __restrict__ cnt) {
    __shared__ int lc[256];
    int b = blockIdx.x, tid = threadIdx.x;
    lc[tid] = 0;
    __syncthreads();
    int s0 = bstart[b], s1 = bstart[b + 1];
    int nbase = b << BSH;
    for (int e = s0 + tid; e < s1; e += 256)
        atomicAdd(&lc[(int)(pairs[e] >> 32) - nbase], 1);
    __syncthreads();
    int node = nbase + tid;
    if (node < N_NODES) cnt[node] = lc[tid];
}

__global__ void k_scan_blk(const int* __restrict__ cnt, int* __restrict__ cursor,
                           int* __restrict__ blks) {
    __shared__ int s[256];
    int tid = threadIdx.x;
    int base = blockIdx.x * SCAN_ITEMS + tid * 4;
    int a0 = (base + 0 < N_NODES) ? cnt[base + 0] : 0;
    int a1 = (base + 1 < N_NODES) ? cnt[base + 1] : 0;
    int a2 = (base + 2 < N_NODES) ? cnt[base + 2] : 0;
    int a3 = (base + 3 < N_NODES) ? cnt[base + 3] : 0;
    int tsum = a0 + a1 + a2 + a3;
    s[tid] = tsum;
    __syncthreads();
    for (int off = 1; off < 256; off <<= 1) {
        int t = (tid >= off) ? s[tid - off] : 0;
        __syncthreads();
        s[tid] += t;
        __syncthreads();
    }
    int texcl = s[tid] - tsum;
    if (base + 0 < N_NODES) cursor[base + 0] = texcl;
    if (base + 1 < N_NODES) cursor[base + 1] = texcl + a0;
    if (base + 2 < N_NODES) cursor[base + 2] = texcl + a0 + a1;
    if (base + 3 < N_NODES) cursor[base + 3] = texcl + a0 + a1 + a2;
    if (tid == 0) blks[blockIdx.x] = s[255];
}

__global__ void k_scan_top(int* __restrict__ blks) {
    __shared__ int s[128];
    int tid = threadIdx.x;
    int v = (tid < NB) ? blks[tid] : 0;
    s[tid] = v;
    __syncthreads();
    for (int off = 1; off < 128; off <<= 1) {
        int t = (tid >= off) ? s[tid - off] : 0;
        __syncthreads();
        s[tid] += t;
        __syncthreads();
    }
    if (tid < NB) blks[tid] = s[tid] - v;
}

__global__ void k_scan_add(const int* __restrict__ cnt, int* __restrict__ cursor,
                           const int* __restrict__ blks, float* __restrict__ dinv) {
    int tid = threadIdx.x;
    int base = blockIdx.x * SCAN_ITEMS + tid * 4;
    int off = blks[blockIdx.x];
#pragma unroll
    for (int j = 0; j < 4; ++j) {
        int i = base + j;
        if (i < N_NODES) {
            cursor[i] += off;
            dinv[i] = rsqrtf(1.0f + (float)cnt[i]);
        }
    }
}

__global__ void k_bfill(const unsigned long long* __restrict__ pairs,
                        const int* __restrict__ bstart, const int* __restrict__ cursor,
                        int* __restrict__ esrc) {
    __shared__ int lcur[256];
    int b = blockIdx.x, tid = threadIdx.x;
    int nbase = b << BSH;
    int node = nbase + tid;
    lcur[tid] = (node < N_NODES) ? cursor[node] : 0;
    __syncthreads();
    int s0 = bstart[b], s1 = bstart[b + 1];
    for (int e = s0 + tid; e < s1; e += 256) {
        unsigned long long p = pairs[e];
        int d = (int)(p >> 32);
        int s = (int)(p & 0xffffffffu);
        int pos = atomicAdd(&lcur[d - nbase], 1);
        esrc[pos] = s;
    }
}

// ---------------------------------------------------------------------------
// MFMA GEMM1 + int8 quantization:
//   v[n,c] = dinv[n] * (x[n,:] @ W1)[c]   (fp32)
//   scale[n] = rowmax(|v|)/127 ;  g1q[n,c] = int8(round(v/scale))
// One wave/block; LDS repack for coalesced uint4 stores.
// ---------------------------------------------------------------------------
__global__ void k_gemm1_mfma(const float* __restrict__ x, const half_t* __restrict__ W1T,
                             const float* __restrict__ dinv, signed char* __restrict__ g1q,
                             float* __restrict__ scales) {
    __shared__ __align__(16) signed char lq[16 * HID_C];
    int lane = threadIdx.x & 63;
    int l16  = lane & 15;
    int lg   = lane >> 4;

    half8 bf[4][4];
#pragma unroll
    for (int ct = 0; ct < 4; ++ct)
#pragma unroll
        for (int kc = 0; kc < 4; ++kc)
            bf[ct][kc] = *(const half8*)(W1T + (ct * 16 + l16) * IN_C + kc * 32 + lg * 8);

#pragma unroll
    for (int s = 0; s < 2; ++s) {
        int r0 = (blockIdx.x * 2 + s) * 16;
        f32x4 acc0 = {0.f, 0.f, 0.f, 0.f};
        f32x4 acc1 = {0.f, 0.f, 0.f, 0.f};
        f32x4 acc2 = {0.f, 0.f, 0.f, 0.f};
        f32x4 acc3 = {0.f, 0.f, 0.f, 0.f};
#pragma unroll
        for (int kc = 0; kc < 4; ++kc) {
            const float* ap = x + (size_t)(r0 + l16) * IN_C + kc * 32 + lg * 8;
            float4 a0 = *(const float4*)ap;
            float4 a1 = *(const float4*)(ap + 4);
            half8 af;
            af[0] = (_Float16)a0.x; af[1] = (_Float16)a0.y;
            af[2] = (_Float16)a0.z; af[3] = (_Float16)a0.w;
            af[4] = (_Float16)a1.x; af[5] = (_Float16)a1.y;
            af[6] = (_Float16)a1.z; af[7] = (_Float16)a1.w;
            acc0 = __builtin_amdgcn_mfma_f32_16x16x32_f16(af, bf[0][kc], acc0, 0, 0, 0);
            acc1 = __builtin_amdgcn_mfma_f32_16x16x32_f16(af, bf[1][kc], acc1, 0, 0, 0);
            acc2 = __builtin_amdgcn_mfma_f32_16x16x32_f16(af, bf[2][kc], acc2, 0, 0, 0);
            acc3 = __builtin_amdgcn_mfma_f32_16x16x32_f16(af, bf[3][kc], acc3, 0, 0, 0);
        }
        // C/D layout: col = lane&15 (+16*ct), row = lg*4 + reg
#pragma unroll
        for (int j = 0; j < 4; ++j) {
            int   r  = r0 + lg * 4 + j;
            float dv = dinv[r];
            float v0 = acc0[j] * dv;
            float v1 = acc1[j] * dv;
            float v2 = acc2[j] * dv;
            float v3 = acc3[j] * dv;
            // row max over the 16 l16-lanes (same lg group)
            float m = fmaxf(fmaxf(fabsf(v0), fabsf(v1)), fmaxf(fabsf(v2), fabsf(v3)));
            m = fmaxf(m, __shfl_xor(m, 1));
            m = fmaxf(m, __shfl_xor(m, 2));
            m = fmaxf(m, __shfl_xor(m, 4));
            m = fmaxf(m, __shfl_xor(m, 8));
            float inv = (m > 0.0f) ? 127.0f / m : 0.0f;
            if (l16 == 0) scales[r] = m * (1.0f / 127.0f);
            int q0 = __float2int_rn(v0 * inv);
            int q1 = __float2int_rn(v1 * inv);
            int q2 = __float2int_rn(v2 * inv);
            int q3 = __float2int_rn(v3 * inv);
            q0 = min(127, max(-127, q0));
            q1 = min(127, max(-127, q1));
            q2 = min(127, max(-127, q2));
            q3 = min(127, max(-127, q3));
            int rl = lg * 4 + j;
            lq[rl * HID_C +  0 + l16] = (signed char)q0;
            lq[rl * HID_C + 16 + l16] = (signed char)q1;
            lq[rl * HID_C + 32 + l16] = (signed char)q2;
            lq[rl * HID_C + 48 + l16] = (signed char)q3;
        }
        // single wave: compiler orders LDS write->read within the wave
        uint4 wv = *(const uint4*)(lq + lane * 16);
        *(uint4*)(g1q + (size_t)r0 * HID_C + lane * 16) = wv;
    }
}

// ---------------------------------------------------------------------------
// pull layer1 + fused 64->40 GEMM.
// g1q rows = 64B int8; 4 slots x 16 lanes x uint (4 ch). Dequant by row scale
// (scales array = 400KB, L2-resident). fp32 accumulate; butterfly combine.
// ---------------------------------------------------------------------------
__global__ void k_pull1(const int* __restrict__ cursor, const int* __restrict__ cnt,
                        const int* __restrict__ esrc, const float* __restrict__ dinv,
                        const unsigned* __restrict__ g1v, const float* __restrict__ scales,
                        const float* __restrict__ b1, const float* __restrict__ W2,
                        half_t* __restrict__ g2) {
    __shared__ float lds[4][HID_C];
    int w    = threadIdx.x >> 6;
    int lane = threadIdx.x & 63;
    int n    = blockIdx.x * 4 + w;
    int h    = lane >> 4;    // slot 0..3
    int c4   = lane & 15;    // channel quad

    float dn  = dinv[n];
    int start = cursor[n];
    int end   = start + cnt[n];

    float4 acc = {0.f, 0.f, 0.f, 0.f};
    if (h == 0)
        acc_q(acc, g1v[(size_t)n * 16 + c4], scales[n], true);  // self row

    int e = start;
    for (; e + 8 <= end; e += 8) {
        int i0 = esrc[e + h];
        int i1 = esrc[e + h + 4];
        unsigned v0 = g1v[(size_t)i0 * 16 + c4];
        float    s0 = scales[i0];
        unsigned v1 = g1v[(size_t)i1 * 16 + c4];
        float    s1 = scales[i1];
        acc_q(acc, v0, s0, true);
        acc_q(acc, v1, s1, true);
    }
    for (; e < end; e += 4) {
        int  ee  = e + h;
        bool ok  = ee < end;
        int  idx = esrc[ok ? ee : end - 1];
        unsigned v = g1v[(size_t)idx * 16 + c4];
        float    s = scales[idx];
        acc_q(acc, v, s, ok);
    }

    // butterfly over slot bits
    acc.x += __shfl_xor(acc.x, 16); acc.y += __shfl_xor(acc.y, 16);
    acc.z += __shfl_xor(acc.z, 16); acc.w += __shfl_xor(acc.w, 16);
    acc.x += __shfl_xor(acc.x, 32); acc.y += __shfl_xor(acc.y, 32);
    acc.z += __shfl_xor(acc.z, 32); acc.w += __shfl_xor(acc.w, 32);

    if (h == 0) {
        float4 bb = ((const float4*)b1)[c4];
        float4 r;
        r.x = fmaxf(dn * acc.x + bb.x, 0.0f);
        r.y = fmaxf(dn * acc.y + bb.y, 0.0f);
        r.z = fmaxf(dn * acc.z + bb.z, 0.0f);
        r.w = fmaxf(dn * acc.w + bb.w, 0.0f);
        ((float4*)lds[w])[c4] = r;
    }
    // wave-private LDS; same-wave write->read ordering handled by compiler
    float s = 0.0f;
#pragma unroll
    for (int c = 0; c < HID_C; ++c)
        s += lds[w][c] * W2[c * OUT_C + (lane < OUT_C ? lane : 0)];
    if (lane < OUT_C)
        g2[(size_t)n * OUT_C + lane] = (half_t)(dn * s);
}

// ---------------------------------------------------------------------------
// pull layer2 -> out. 3 edges per wave (20 lanes x 4B = 80B packed row).
// ---------------------------------------------------------------------------
__global__ void k_pull2(const int* __restrict__ cursor, const int* __restrict__ cnt,
                        const int* __restrict__ esrc, const float* __restrict__ dinv,
                        const half_t* __restrict__ g2, const float* __restrict__ b2,
                        float* __restrict__ out) {
    int w    = threadIdx.x >> 6;
    int lane = threadIdx.x & 63;
    int n    = blockIdx.x * 4 + w;
    int slot = lane / 20;            // 0..2 active, 3 idle
    int c2   = lane - slot * 20;     // channel pair 0..19
    const unsigned* g2u = (const unsigned*)g2;

    float dn  = dinv[n];
    int start = cursor[n];
    int end   = start + cnt[n];

    float2 acc = {0.f, 0.f};
    if (slot == 0) acc_pair(acc, g2u[(size_t)n * 20 + c2]);  // self row

    if (slot < 3) {
        int e = start + slot;
        for (; e + 9 < end; e += 12) {
            int s0 = esrc[e], s1 = esrc[e + 3], s2 = esrc[e + 6], s3 = esrc[e + 9];
            unsigned v0 = g2u[(size_t)s0 * 20 + c2];
            unsigned v1 = g2u[(size_t)s1 * 20 + c2];
            unsigned v2 = g2u[(size_t)s2 * 20 + c2];
            unsigned v3 = g2u[(size_t)s3 * 20 + c2];
            acc_pair(acc, v0); acc_pair(acc, v1); acc_pair(acc, v2); acc_pair(acc, v3);
        }
        for (; e < end; e += 3)
            acc_pair(acc, g2u[(size_t)esrc[e] * 20 + c2]);
    }

    float x1 = __shfl(acc.x, c2 + 20);
    float y1 = __shfl(acc.y, c2 + 20);
    float x2 = __shfl(acc.x, c2 + 40);
    float y2 = __shfl(acc.y, c2 + 40);
    if (slot == 0) {
        float2 bb = ((const float2*)b2)[c2];
        float2 r;
        r.x = bb.x + dn * (acc.x + x1 + x2);
        r.y = bb.y + dn * (acc.y + y1 + y2);
        ((float2*)(out + (size_t)n * OUT_C))[c2] = r;
    }
}

// ---------------------------------------------------------------------------
// launch
// ---------------------------------------------------------------------------
extern "C" void kernel_launch(void* const* d_in, const int* in_sizes, int n_in,
                              void* d_out, int out_size, void* d_ws, size_t ws_size,
                              hipStream_t stream) {
    const float* x   = (const float*)d_in[0];
    const int*   ei  = (const int*)d_in[1];
    const int*   src = ei;
    const int*   dst = ei + N_EDGES;
    const float* W1  = (const float*)d_in[2];
    const float* b1  = (const float*)d_in[3];
    const float* W2  = (const float*)d_in[4];
    const float* b2  = (const float*)d_in[5];
    float*       out = (float*)d_out;

    // workspace layout (~29 MB)
    int*    cnt    = (int*)d_ws;                      // N
    int*    cursor = cnt + N_NODES;                   // N
    int*    blks   = cursor + N_NODES;                // 128
    int*    bcnt   = blks + 128;                      // NBUCK
    int*    bstart = bcnt + NBUCK;                    // NBUCK+1
    int*    gcur   = bstart + NBUCK + 1;              // NBUCK
    half_t* w1t    = (half_t*)(gcur + NBUCK);         // 128*64 halves (16KB)
    float*  dinv   = (float*)(w1t + IN_C * HID_C);    // N
    float*  scales = dinv + N_NODES;                  // N
    int*    esrc   = (int*)(scales + N_NODES);        // E
    int*    after  = esrc + N_EDGES;
    unsigned long long* pairs =
        (unsigned long long*)(((uintptr_t)after + 15) & ~(uintptr_t)15);  // E * 8B
    signed char* g1q = (signed char*)pairs;           // 6.4MB, overlays dead pairs
    half_t* g2 = (half_t*)(pairs + N_EDGES);          // N*OUT_C halves (8MB)

    // CSR build (bucketed)
    k_init<<<1, 512, 0, stream>>>(W1, w1t, bcnt);
    k_hist<<<NPB, 256, 0, stream>>>(dst, bcnt);
    k_bscan<<<1, 512, 0, stream>>>(bcnt, bstart, gcur);
    k_part<<<NPB, 256, 0, stream>>>(src, dst, gcur, pairs);
    k_bcount<<<NBUCK, 256, 0, stream>>>(pairs, bstart, cnt);
    k_scan_blk<<<NB, 256, 0, stream>>>(cnt, cursor, blks);
    k_scan_top<<<1, 128, 0, stream>>>(blks);
    k_scan_add<<<NB, 256, 0, stream>>>(cnt, cursor, blks, dinv);
    k_bfill<<<NBUCK, 256, 0, stream>>>(pairs, bstart, cursor, esrc);

    // layer 1 transform: g1q = int8(dinv * (x @ W1)), per-row scales
    k_gemm1_mfma<<<N_NODES / 32, 64, 0, stream>>>(x, w1t, dinv, g1q, scales);

    // pull layer 1 + fused GEMM2
    k_pull1<<<N_NODES / 4, 256, 0, stream>>>(cursor, cnt, esrc, dinv,
                                             (const unsigned*)g1q, scales, b1, W2, g2);

    // pull layer 2
    k_pull2<<<N_NODES / 4, 256, 0, stream>>>(cursor, cnt, esrc, dinv, g2, b2, out);
}